// Round 1
// baseline (246.955 us; speedup 1.0000x reference)
//
#include <hip/hip_runtime.h>
#include <hip/hip_bf16.h>

#define BB 8
#define NN 2048
#define FIN 128
#define FO 64
#define ALPHA 0.2f
#define SPLITS 4

typedef __attribute__((ext_vector_type(8))) short bf16x8;
typedef __attribute__((ext_vector_type(4))) float f32x4;
typedef __attribute__((ext_vector_type(4))) int i32x4;

__device__ inline short f2bf(float x) {
    unsigned u = __float_as_uint(x);
    u += 0x7fffu + ((u >> 16) & 1u);   // RNE; x>=0, no NaN here
    return (short)(u >> 16);
}

// ---------------- Kernel A: Wh = h@W (fp32), whT bf16 [B][FO][N], e1/e2 [B*N] ----
__global__ __launch_bounds__(256) void wh_kernel(
    const float* __restrict__ h, const float* __restrict__ W,
    const float* __restrict__ a, float* __restrict__ e1, float* __restrict__ e2,
    __hip_bfloat16* __restrict__ whT)
{
    __shared__ float hs[32][FIN];
    const int r0 = blockIdx.x * 32;           // 32 rows per block, 32 | N so same batch
    const int t = threadIdx.x;
    // stage 32*128 floats (16 KB) cooperatively, float4
    const float4* hsrc = (const float4*)(h + (size_t)r0 * FIN);
    float4* hdst = (float4*)(&hs[0][0]);
#pragma unroll
    for (int k = 0; k < 4; k++) hdst[t + 256 * k] = hsrc[t + 256 * k];
    __syncthreads();

    const int o = t & 63;
    const int wv = t >> 6;                     // wave id -> rows wv*8 .. wv*8+7
    float acc[8];
#pragma unroll
    for (int rr = 0; rr < 8; rr++) acc[rr] = 0.f;

    for (int f = 0; f < FIN; f += 4) {
        const float w0 = W[(f + 0) * FO + o];
        const float w1 = W[(f + 1) * FO + o];
        const float w2 = W[(f + 2) * FO + o];
        const float w3 = W[(f + 3) * FO + o];
#pragma unroll
        for (int rr = 0; rr < 8; rr++) {
            float4 hv = *(const float4*)&hs[wv * 8 + rr][f];   // wave-uniform addr -> LDS broadcast
            acc[rr] = fmaf(hv.x, w0, acc[rr]);
            acc[rr] = fmaf(hv.y, w1, acc[rr]);
            acc[rr] = fmaf(hv.z, w2, acc[rr]);
            acc[rr] = fmaf(hv.w, w3, acc[rr]);
        }
    }

    const float a1 = a[o], a2 = a[FO + o];
    const int b = r0 / NN;
    const int ib0 = r0 - b * NN;
#pragma unroll
    for (int rr = 0; rr < 8; rr++) {
        const int ib = ib0 + wv * 8 + rr;          // row within batch
        const float w = acc[rr];
        whT[((size_t)(b * FO + o)) * NN + ib] = __float2bfloat16(w);
        float v1 = w * a1, v2 = w * a2;
#pragma unroll
        for (int m = 32; m >= 1; m >>= 1) {
            v1 += __shfl_xor(v1, m, 64);
            v2 += __shfl_xor(v2, m, 64);
        }
        if (o == 0) { e1[r0 + wv * 8 + rr] = v1; e2[r0 + wv * 8 + rr] = v2; }
    }
}

// ---------------- Kernel A2: e2max per batch --------------------------------
__global__ __launch_bounds__(256) void e2max_kernel(
    const float* __restrict__ e2, float* __restrict__ e2max)
{
    const int b = blockIdx.x;
    const int t = threadIdx.x;
    float m = -1e30f;
    for (int j = t; j < NN; j += 256) m = fmaxf(m, e2[b * NN + j]);
#pragma unroll
    for (int k = 32; k >= 1; k >>= 1) m = fmaxf(m, __shfl_xor(m, k, 64));
    __shared__ float red[4];
    if ((t & 63) == 0) red[t >> 6] = m;
    __syncthreads();
    if (t == 0) e2max[b] = fmaxf(fmaxf(red[0], red[1]), fmaxf(red[2], red[3]));
}

// ---------------- Kernel B: fused masked softmax-numerator PV (MFMA bf16) ---
// wave task = (b, i-tile of 16 rows, j-split). Scores generated straight into
// A-fragment registers; B-fragments are 16B loads from whT (L2-resident).
__global__ __launch_bounds__(256) void attn_kernel(
    const int* __restrict__ adj, const float* __restrict__ e1,
    const float* __restrict__ e2, const float* __restrict__ e2max,
    const __hip_bfloat16* __restrict__ whT,
    float* __restrict__ acc_ws,   // [SPLITS][B*N][FO]
    float* __restrict__ l_ws)     // [SPLITS][B*N]
{
    const int t = threadIdx.x;
    const int wave = t >> 6, lane = t & 63;
    const int w = blockIdx.x * 4 + wave;        // 4096 wave tasks
    const int s  = w & (SPLITS - 1);
    const int it = (w >> 2) & 127;
    const int b  = w >> 9;
    const int i0 = it * 16;
    const int m = lane & 15, q = lane >> 4;
    const int i = i0 + m;                        // row this lane scores

    const float e1v = e1[b * NN + i];
    float mi = e1v + e2max[b];
    mi = mi > 0.f ? mi : ALPHA * mi;             // safe per-row max bound

    const int jbase = s * (NN / SPLITS);
    const int* adjrow = adj + ((size_t)(b * NN + i)) * NN;
    const float* e2b = e2 + b * NN;
    const short* wT = (const short*)(whT + (size_t)b * FO * NN);

    f32x4 acc0 = {0.f,0.f,0.f,0.f}, acc1 = acc0, acc2 = acc0, acc3 = acc0;
    float lsum = 0.f;

    for (int j0 = jbase; j0 < jbase + NN / SPLITS; j0 += 32) {
        const int jq = j0 + q * 8;               // this lane's 8 k's
        i32x4 ad0 = *(const i32x4*)(adjrow + jq);
        i32x4 ad1 = *(const i32x4*)(adjrow + jq + 4);
        f32x4 ev0 = *(const f32x4*)(e2b + jq);
        f32x4 ev1 = *(const f32x4*)(e2b + jq + 4);

        bf16x8 af;
#pragma unroll
        for (int jj = 0; jj < 8; jj++) {
            const int   av = (jj < 4) ? ad0[jj] : ad1[jj - 4];
            const float e2j = (jj < 4) ? ev0[jj] : ev1[jj - 4];
            float e = e1v + e2j;
            e = e > 0.f ? e : ALPHA * e;
            const float pe = (av > 0) ? __expf(e - mi) : 0.f;
            lsum += pe;
            af[jj] = f2bf(pe);
        }

        bf16x8 b0 = *(const bf16x8*)(wT + (size_t)( 0 + m) * NN + jq);
        bf16x8 b1 = *(const bf16x8*)(wT + (size_t)(16 + m) * NN + jq);
        bf16x8 b2 = *(const bf16x8*)(wT + (size_t)(32 + m) * NN + jq);
        bf16x8 b3 = *(const bf16x8*)(wT + (size_t)(48 + m) * NN + jq);

        acc0 = __builtin_amdgcn_mfma_f32_16x16x32_bf16(af, b0, acc0, 0, 0, 0);
        acc1 = __builtin_amdgcn_mfma_f32_16x16x32_bf16(af, b1, acc1, 0, 0, 0);
        acc2 = __builtin_amdgcn_mfma_f32_16x16x32_bf16(af, b2, acc2, 0, 0, 0);
        acc3 = __builtin_amdgcn_mfma_f32_16x16x32_bf16(af, b3, acc3, 0, 0, 0);
    }

    // l: reduce across the 4 quads holding the same row m
    lsum += __shfl_xor(lsum, 16, 64);
    lsum += __shfl_xor(lsum, 32, 64);
    if (q == 0) l_ws[(size_t)s * BB * NN + b * NN + i] = lsum;

    // D layout: row = q*4 + reg, col = m (per o-tile)
    float* aout = acc_ws + ((size_t)s * BB * NN + b * NN) * FO;
#pragma unroll
    for (int ot = 0; ot < 4; ot++) {
        f32x4 av = (ot == 0) ? acc0 : (ot == 1) ? acc1 : (ot == 2) ? acc2 : acc3;
#pragma unroll
        for (int reg = 0; reg < 4; reg++) {
            const int row = i0 + q * 4 + reg;
            aout[(size_t)row * FO + ot * 16 + m] = av[reg];
        }
    }
}

// ---------------- Kernel C: combine splits, normalize, ELU ------------------
__global__ __launch_bounds__(256) void final_kernel(
    const float* __restrict__ acc_ws, const float* __restrict__ l_ws,
    float* __restrict__ out)
{
    const int gid = blockIdx.x * 256 + threadIdx.x;   // B*N*FO = 1M
    const int r = gid >> 6, o = gid & 63;
    float sum = 0.f;
#pragma unroll
    for (int s = 0; s < SPLITS; s++) sum += acc_ws[((size_t)s * BB * NN + r) * FO + o];
    float l = 0.f;
#pragma unroll
    for (int s = 0; s < SPLITS; s++) l += l_ws[(size_t)s * BB * NN + r];
    l = fmaxf(l, 1e-38f);
    const float v = sum / l;
    out[gid] = v > 0.f ? v : (__expf(v) - 1.f);       // ELU, alpha=1
}

extern "C" void kernel_launch(void* const* d_in, const int* in_sizes, int n_in,
                              void* d_out, int out_size, void* d_ws, size_t ws_size,
                              hipStream_t stream) {
    const float* h   = (const float*)d_in[0];
    const int*   adj = (const int*)d_in[1];
    const float* W   = (const float*)d_in[2];
    const float* a   = (const float*)d_in[3];
    float* out = (float*)d_out;

    char* ws = (char*)d_ws;
    __hip_bfloat16* whT = (__hip_bfloat16*)ws;                 // 2 MB
    size_t off = (size_t)BB * FO * NN * sizeof(__hip_bfloat16);
    float* e1 = (float*)(ws + off);  off += (size_t)BB * NN * 4;
    float* e2 = (float*)(ws + off);  off += (size_t)BB * NN * 4;
    float* e2m = (float*)(ws + off); off += 256;
    float* acc_ws = (float*)(ws + off); off += (size_t)SPLITS * BB * NN * FO * 4;
    float* l_ws = (float*)(ws + off);

    wh_kernel<<<(BB * NN) / 32, 256, 0, stream>>>(h, W, a, e1, e2, whT);
    e2max_kernel<<<BB, 256, 0, stream>>>(e2, e2m);
    attn_kernel<<<(BB * (NN / 16) * SPLITS) / 4, 256, 0, stream>>>(adj, e1, e2, e2m, whT, acc_ws, l_ws);
    final_kernel<<<(BB * NN * FO) / 256, 256, 0, stream>>>(acc_ws, l_ws, out);
}

// Round 2
// 217.205 us; speedup vs baseline: 1.1370x; 1.1370x over previous
//
#include <hip/hip_runtime.h>
#include <hip/hip_bf16.h>

#define BB 8
#define NN 2048
#define FIN 128
#define FO 64
#define ALPHA 0.2f

typedef __attribute__((ext_vector_type(8))) short bf16x8;
typedef __attribute__((ext_vector_type(4))) float f32x4;
typedef __attribute__((ext_vector_type(4))) int i32x4;

typedef __attribute__((address_space(1))) const void gvoid;
typedef __attribute__((address_space(3))) void lvoid;

__device__ inline void gl_lds16(const void* g, void* l) {
    // async global->LDS, 16B per lane; LDS dest = uniform base + lane*16
    __builtin_amdgcn_global_load_lds((gvoid*)g, (lvoid*)l, 16, 0, 0);
}

__device__ inline short f2bf(float x) {
    unsigned u = __float_as_uint(x);
    u += 0x7fffu + ((u >> 16) & 1u);   // RNE, sign-agnostic, no NaN inputs here
    return (short)(u >> 16);
}

// ---------------- Kernel A: Wh = h@W; whF in MFMA B-fragment layout ----------
// whF[b][jc][ot][lane][8] shorts: lane L holds Wh[b][j=jc*32+(L>>4)*8+jj][o=ot*16+(L&15)]
__global__ __launch_bounds__(256) void wh_kernel(
    const float* __restrict__ h, const float* __restrict__ W,
    const float* __restrict__ a, float* __restrict__ e1, float* __restrict__ e2,
    short* __restrict__ whF)
{
    __shared__ float hs[32][FIN];
    const int r0 = blockIdx.x * 32;           // 32 rows per block (same batch)
    const int t = threadIdx.x;
    const float4* hsrc = (const float4*)(h + (size_t)r0 * FIN);
    float4* hdst = (float4*)(&hs[0][0]);
#pragma unroll
    for (int k = 0; k < 4; k++) hdst[t + 256 * k] = hsrc[t + 256 * k];
    __syncthreads();

    const int o = t & 63;
    const int wv = t >> 6;                     // rows wv*8 .. wv*8+7
    float acc[8];
#pragma unroll
    for (int rr = 0; rr < 8; rr++) acc[rr] = 0.f;

    for (int f = 0; f < FIN; f += 4) {
        const float w0 = W[(f + 0) * FO + o];
        const float w1 = W[(f + 1) * FO + o];
        const float w2 = W[(f + 2) * FO + o];
        const float w3 = W[(f + 3) * FO + o];
#pragma unroll
        for (int rr = 0; rr < 8; rr++) {
            float4 hv = *(const float4*)&hs[wv * 8 + rr][f];
            acc[rr] = fmaf(hv.x, w0, acc[rr]);
            acc[rr] = fmaf(hv.y, w1, acc[rr]);
            acc[rr] = fmaf(hv.z, w2, acc[rr]);
            acc[rr] = fmaf(hv.w, w3, acc[rr]);
        }
    }

    // fragment-layout store: one contiguous 16B per lane
    const int b   = r0 / NN;
    const int ib0 = r0 - b * NN;
    const int ibb = ib0 + wv * 8;              // first row this wave owns (mult of 8)
    const int jc  = ibb >> 5;
    const int qq  = (ibb >> 3) & 3;
    const int ot  = o >> 4, mm = o & 15;
    const int L   = mm + qq * 16;
    bf16x8 frag;
#pragma unroll
    for (int rr = 0; rr < 8; rr++) frag[rr] = f2bf(acc[rr]);
    *(bf16x8*)(whF + ((((size_t)(b * 64 + jc) * 4 + ot) * 64 + L) * 8)) = frag;

    const float a1 = a[o], a2 = a[FO + o];
#pragma unroll
    for (int rr = 0; rr < 8; rr++) {
        float v1 = acc[rr] * a1, v2 = acc[rr] * a2;
#pragma unroll
        for (int msk = 32; msk >= 1; msk >>= 1) {
            v1 += __shfl_xor(v1, msk, 64);
            v2 += __shfl_xor(v2, msk, 64);
        }
        if (o == 0) { e1[r0 + wv * 8 + rr] = v1; e2[r0 + wv * 8 + rr] = v2; }
    }
}

// ---------------- Kernel A2: e2max per batch --------------------------------
__global__ __launch_bounds__(256) void e2max_kernel(
    const float* __restrict__ e2, float* __restrict__ e2max)
{
    const int b = blockIdx.x;
    const int t = threadIdx.x;
    float m = -1e30f;
    for (int j = t; j < NN; j += 256) m = fmaxf(m, e2[b * NN + j]);
#pragma unroll
    for (int k = 32; k >= 1; k >>= 1) m = fmaxf(m, __shfl_xor(m, k, 64));
    __shared__ float red[4];
    if ((t & 63) == 0) red[t >> 6] = m;
    __syncthreads();
    if (t == 0) e2max[b] = fmaxf(fmaxf(red[0], red[1]), fmaxf(red[2], red[3]));
}

// ---------------- Kernel B: fused attention (coalesced, LDS-staged) ---------
// block = (b, 16-row i-tile); 4 waves split j; combine+normalize+ELU in-block.
struct SMemS { int adj[16][260]; float e2[256]; };
struct SMemC { float comb[4][16][64]; float lsum[4][16]; };
union SMemU { SMemS s; SMemC c; };

__global__ __launch_bounds__(256) void attn_kernel(
    const int* __restrict__ adj, const float* __restrict__ e1,
    const float* __restrict__ e2, const float* __restrict__ e2max,
    const short* __restrict__ whF, float* __restrict__ out)
{
    __shared__ SMemU sm;
    const int t = threadIdx.x, w = t >> 6, lane = t & 63;
    const int m = lane & 15, q = lane >> 4;
    const int blk = blockIdx.x;
    const int b  = blk >> 7;
    const int i0 = (blk & 127) * 16;
    const int i  = i0 + m;

    const float e1v = e1[b * NN + i];
    float mi = e1v + e2max[b];
    mi = mi > 0.f ? mi : ALPHA * mi;           // safe per-row max bound (leakyrelu monotone)

    const short* whFb = whF + (size_t)b * (64 * 4 * 64 * 8);
    const int* arow0 = adj + ((size_t)(b * NN + i0)) * NN + lane * 4;  // row 0, lane's 16B
    const float* e2g = e2 + b * NN + lane * 4;

    f32x4 acc0 = {0.f,0.f,0.f,0.f}, acc1 = acc0, acc2 = acc0, acc3 = acc0;
    float lsum = 0.f;

    for (int j0 = 0; j0 < NN; j0 += 256) {
        // stage adj[16][256] (1KB row per wave-instruction) + e2[256]
#pragma unroll
        for (int k = 0; k < 4; k++) {
            const int r = w * 4 + k;
            gl_lds16(arow0 + (size_t)r * NN + j0, &sm.s.adj[r][0]);
        }
        if (w == 0) gl_lds16(e2g + j0, &sm.s.e2[0]);
        __syncthreads();

#pragma unroll
        for (int s2 = 0; s2 < 2; s2++) {
            const int col = w * 64 + s2 * 32 + q * 8;
            i32x4 a0 = *(const i32x4*)&sm.s.adj[m][col];
            i32x4 a1 = *(const i32x4*)&sm.s.adj[m][col + 4];
            f32x4 ev0 = *(const f32x4*)&sm.s.e2[col];
            f32x4 ev1 = *(const f32x4*)&sm.s.e2[col + 4];

            bf16x8 af;
#pragma unroll
            for (int jj = 0; jj < 8; jj++) {
                const int   av  = (jj < 4) ? a0[jj]      : a1[jj - 4];
                const float e2j = (jj < 4) ? ev0[jj]     : ev1[jj - 4];
                float e = e1v + e2j;
                e = e > 0.f ? e : ALPHA * e;
                const float pe = (av > 0) ? __expf(e - mi) : 0.f;
                lsum += pe;
                af[jj] = f2bf(pe);
            }

            const int jc = (j0 + w * 64 + s2 * 32) >> 5;
            const short* bfp = whFb + (size_t)jc * 2048 + lane * 8;
            bf16x8 b0 = *(const bf16x8*)(bfp);
            bf16x8 b1 = *(const bf16x8*)(bfp + 512);
            bf16x8 b2 = *(const bf16x8*)(bfp + 1024);
            bf16x8 b3 = *(const bf16x8*)(bfp + 1536);

            acc0 = __builtin_amdgcn_mfma_f32_16x16x32_bf16(af, b0, acc0, 0, 0, 0);
            acc1 = __builtin_amdgcn_mfma_f32_16x16x32_bf16(af, b1, acc1, 0, 0, 0);
            acc2 = __builtin_amdgcn_mfma_f32_16x16x32_bf16(af, b2, acc2, 0, 0, 0);
            acc3 = __builtin_amdgcn_mfma_f32_16x16x32_bf16(af, b3, acc3, 0, 0, 0);
        }
        __syncthreads();   // protect LDS reuse (stage of next step / combine)
    }

    // cross-wave combine in LDS (union reuse; last barrier above fences it)
    lsum += __shfl_xor(lsum, 16, 64);
    lsum += __shfl_xor(lsum, 32, 64);
    if (q == 0) sm.c.lsum[w][m] = lsum;
#pragma unroll
    for (int ot = 0; ot < 4; ot++) {
        f32x4 av = (ot == 0) ? acc0 : (ot == 1) ? acc1 : (ot == 2) ? acc2 : acc3;
#pragma unroll
        for (int reg = 0; reg < 4; reg++)
            sm.c.comb[w][q * 4 + reg][ot * 16 + m] = av[reg];
    }
    __syncthreads();

    const int row = t >> 4, c0 = (t & 15) * 4;
    f32x4 sum = *(const f32x4*)&sm.c.comb[0][row][c0];
#pragma unroll
    for (int ww = 1; ww < 4; ww++) {
        f32x4 sv = *(const f32x4*)&sm.c.comb[ww][row][c0];
        sum.x += sv.x; sum.y += sv.y; sum.z += sv.z; sum.w += sv.w;
    }
    float l = sm.c.lsum[0][row] + sm.c.lsum[1][row] + sm.c.lsum[2][row] + sm.c.lsum[3][row];
    l = fmaxf(l, 1e-30f);
    const float rl = 1.f / l;
    float vr[4] = { sum.x * rl, sum.y * rl, sum.z * rl, sum.w * rl };
    f32x4 res;
#pragma unroll
    for (int kk = 0; kk < 4; kk++)
        res[kk] = vr[kk] > 0.f ? vr[kk] : (__expf(vr[kk]) - 1.f);
    *(f32x4*)&out[((size_t)(b * NN + i0 + row)) * FO + c0] = res;
}

extern "C" void kernel_launch(void* const* d_in, const int* in_sizes, int n_in,
                              void* d_out, int out_size, void* d_ws, size_t ws_size,
                              hipStream_t stream) {
    const float* h   = (const float*)d_in[0];
    const int*   adj = (const int*)d_in[1];
    const float* W   = (const float*)d_in[2];
    const float* a   = (const float*)d_in[3];
    float* out = (float*)d_out;

    char* ws = (char*)d_ws;
    short* whF = (short*)ws;                                   // 2 MB
    size_t off = (size_t)BB * 64 * 4 * 64 * 8 * sizeof(short);
    float* e1  = (float*)(ws + off);  off += (size_t)BB * NN * 4;
    float* e2  = (float*)(ws + off);  off += (size_t)BB * NN * 4;
    float* e2m = (float*)(ws + off);

    wh_kernel<<<(BB * NN) / 32, 256, 0, stream>>>(h, W, a, e1, e2, whF);
    e2max_kernel<<<BB, 256, 0, stream>>>(e2, e2m);
    attn_kernel<<<BB * (NN / 16), 256, 0, stream>>>(adj, e1, e2, e2m, whF, out);
}